// Round 12
// baseline (149.301 us; speedup 1.0000x reference)
//
#include <hip/hip_runtime.h>
#include <hip/hip_fp16.h>

#define HC 16
#define CIN 16
#define BD 31
#define HH 128
#define WW 128
#define PLANE (HH*WW)           // 16384
#define CH_STRIDE (BD*PLANE)    // 507904

typedef __attribute__((ext_vector_type(8))) short bf16x8;   // 8 bf16 = 4 VGPR
typedef __attribute__((ext_vector_type(16))) float f32x16;  // MFMA 32x32 acc

__device__ __forceinline__ float sigmoid_fast(float x) {
    return __builtin_amdgcn_rcpf(1.0f + __expf(-x));
}
__device__ __forceinline__ float tanh_fast(float x) {
    return fmaf(2.0f, __builtin_amdgcn_rcpf(1.0f + __expf(-2.0f * x)), -1.0f);
}
__device__ __forceinline__ ushort f2bf(float f) {   // RNE float->bf16 (prep paths)
    unsigned u = __float_as_uint(f);
    u = (u + 0x7fffu + ((u >> 16) & 1u)) >> 16;
    return (ushort)u;
}
// packed f32x2 -> bf16x2 via HW cvt_pk (no builtin on gfx950 — inline asm, T12)
__device__ __forceinline__ unsigned pack_bf2(float lo, float hi) {
    unsigned r;
    asm("v_cvt_pk_bf16_f32 %0, %1, %2" : "=v"(r) : "v"(lo), "v"(hi));
    return r;
}
// exact-gelu via Abramowitz-Stegun 7.1.26 erf (|eps|<=1.5e-7)
__device__ __forceinline__ float gelu_as(float s) {
    float z  = 0.70710678118f * s;
    float az = fabsf(z);
    float t  = __builtin_amdgcn_rcpf(fmaf(0.3275911f, az, 1.0f));
    float p  = t * (0.254829592f + t * (-0.284496736f + t * (1.421413741f
             + t * (-1.453152027f + t * 1.061405429f))));
    float e  = __expf(-z * z);
    float er = copysignf(1.0f - p * e, z);
    return 0.5f * s * (1.0f + er);
}

// ---------------------------------------------------------------------------
// xprep + weight prep in ONE launch. Blocks < 7936: fp32 -> bf16 rows
// xT[b][d][h][4096B] with the slab swizzle pre-baked. Blocks >= 7936 (62):
// conv wtab (co=lane&31, ci=8*(lane>>5)+j) and MLP wtab2 with the shared
// k-map k(e,hi)=(e&3)+8*(e>>2)+4*hi on all tables.
// ---------------------------------------------------------------------------
__global__ __launch_bounds__(256)
void xprep_kernel(const float* __restrict__ inp, char* __restrict__ xT,
                  const float* __restrict__ cw,
                  const float* __restrict__ w1,
                  const float* __restrict__ w2,
                  const float* __restrict__ w3,
                  ushort* __restrict__ wtab, ushort* __restrict__ wtab2)
{
    if (blockIdx.x >= 7936) {                 // weight-prep blocks
        int idx = (blockIdx.x - 7936) * 256 + threadIdx.x;
        if (idx < 13824) {
            int j    = idx & 7;
            int lane = (idx >> 3) & 63;
            int t    = (idx >> 9) % 9;
            int kd   = (idx >> 9) / 9;
            int co = lane & 31;
            int ci = 8 * (lane >> 5) + j;
            int kh = t / 3, kw = t % 3;
            wtab[idx] = f2bf(cw[(co * CIN + ci) * 27 + kd * 9 + kh * 3 + kw]);
            return;
        }
        idx -= 13824;
        if (idx >= 2048) return;
        int e    = idx & 7;
        int lane = (idx >> 3) & 63;
        int tbl  = idx >> 9;
        int m  = lane & 31;
        int hi = lane >> 5;
        int k  = (e & 3) + 8 * (e >> 2) + 4 * hi;   // shared k-permutation
        float v = 0.f;
        if (tbl == 0)      v = w1[k * 32 + m];
        else if (tbl == 3) v = w3[k * 32 + m];
        else {
            int mf = tbl - 1;
            if (m < 16) v = w2[(k + 16 * mf) * 16 + m];
        }
        wtab2[idx] = f2bf(v);
        return;
    }

    __shared__ float tile[16][256];
    int t  = threadIdx.x;
    int hp = blockIdx.x & 63;
    int g  = blockIdx.x >> 6;
    int d  = g % BD;
    int b  = g / BD;

    size_t src = (size_t)b * CIN * CH_STRIDE + (size_t)d * PLANE + hp * 256;
    #pragma unroll
    for (int c = 0; c < 16; ++c)
        tile[c][t] = inp[src + (size_t)c * CH_STRIDE + t];
    __syncthreads();

    int w  = t & 127;
    int rr = t >> 7;
    char* rowp = xT + (((size_t)(b * BD + d) * 128) + hp * 2 + rr) * 4096;
    #pragma unroll
    for (int q = 0; q < 2; ++q) {
        uint4 pk;
        pk.x = (unsigned)f2bf(tile[q*8+0][t]) | ((unsigned)f2bf(tile[q*8+1][t]) << 16);
        pk.y = (unsigned)f2bf(tile[q*8+2][t]) | ((unsigned)f2bf(tile[q*8+3][t]) << 16);
        pk.z = (unsigned)f2bf(tile[q*8+4][t]) | ((unsigned)f2bf(tile[q*8+5][t]) << 16);
        pk.w = (unsigned)f2bf(tile[q*8+6][t]) | ((unsigned)f2bf(tile[q*8+7][t]) << 16);
        unsigned off = ((unsigned)((w + 1) * 32 + q * 16) ^ (((unsigned)(w + 1) & 0xE) << 3)) - 32;
        *(uint4*)(rowp + off) = pk;
    }
}

// ---------------------------------------------------------------------------
// Kernel B: FUSED conv+scan (MLP split out — it has no serial dependency and
// was trapping 16 gelu/lane inside the 2-wave/SIMD scan loop). Pipelined:
// conv(d)'s 27 MFMAs interleave with tail(d-1)'s gates/scan (T15). Tail now:
// 8 gates + cvt_pk + ONE 16B store of bf16 h (hbuf[bd][pix][16ch], 2KB/wave).
// ---------------------------------------------------------------------------
#define SLOT_B (3 * 4224)       // 12672 B per plane slot

__device__ __forceinline__ void gload_lds16(const void* g, void* l) {
    __builtin_amdgcn_global_load_lds(
        (const __attribute__((address_space(1))) unsigned int*)g,
        (__attribute__((address_space(3))) unsigned int*)l, 16, 0, 0);
}

__global__ __launch_bounds__(256, 2)
void qrnn_convscan(const char* __restrict__ xT,
                   const ushort* __restrict__ wtab,
                   char* __restrict__ hbuf,
                   const int* __restrict__ rev_p)
{
    __shared__ __align__(16) char slab[4][SLOT_B];

    // grid 512 = 8 XCD x 64
    int p = blockIdx.x;
    int logical = (p & 7) * 64 + (p >> 3);
    int b  = logical >> 7;
    int ht = logical & 127;
    int rev = rev_p[0];

    int lane = threadIdx.x & 63;
    int wid  = threadIdx.x >> 6;
    int wl   = lane & 31;
    int hi   = lane >> 5;
    int cio  = hi * 16;

    const bf16x8* wt = (const bf16x8*)wtab;
    bf16x8 af[27];
    #pragma unroll
    for (int t = 0; t < 27; ++t) af[t] = wt[t * 64 + lane];

    unsigned bpo[3];
    #pragma unroll
    for (int dwn = 0; dwn < 3; ++dwn) {
        unsigned wc = (unsigned)(wl + dwn);
        bpo[dwn] = (unsigned)(wid * 1024) + ((wc * 32 + cio) ^ ((wc & 0xE) << 3));
    }

    for (int i = threadIdx.x; i < 4 * 3 * 32; i += 256) {
        int s = i / 96;
        int r = (i / 32) % 3;
        int k = i & 31;
        int off = (k < 8) ? (k * 4) : (4128 + (k - 8) * 4);
        *(int*)(slab[s] + r * 4224 + off) = 0;
    }

    auto zero_slot = [&](int s) {
        for (int i = threadIdx.x; i < 768; i += 256) {
            int r = i >> 8;
            int k = i & 255;
            *(uint4*)(slab[s] + r * 4224 + 32 + k * 16) = uint4{0, 0, 0, 0};
        }
    };

    auto stage = [&](int s, int plane) {
        const char* pl = xT + ((size_t)(b * BD + plane) * 128) * 4096;
        for (int c = wid; c < 12; c += 4) {
            int rr = c >> 2, ch = c & 3;
            int h = ht - 1 + rr;
            char* dst = slab[s] + rr * 4224 + 32 + ch * 1024;
            if ((unsigned)h < (unsigned)HH)
                gload_lds16(pl + (size_t)h * 4096 + ch * 1024 + lane * 16, dst);
            else
                *(uint4*)(dst + lane * 16) = uint4{0, 0, 0, 0};
        }
    };

    f32x16 zacc;
    #pragma unroll
    for (int r = 0; r < 16; ++r) zacc[r] = 0.f;

    auto convd = [&](int d) -> f32x16 {
        f32x16 A = zacc;
        #pragma unroll
        for (int kd = 0; kd < 3; ++kd) {
            const char* sb = slab[(d - 1 + kd) & 3];
            #pragma unroll
            for (int t = 0; t < 9; ++t) {
                bf16x8 bfr = *(const bf16x8*)(sb + (t / 3) * 4224 + bpo[t % 3]);
                A = __builtin_amdgcn_mfma_f32_32x32x16_bf16(af[kd * 9 + t], bfr, A, 0, 0, 0);
            }
        }
        return A;
    };

    float h[8];
    #pragma unroll
    for (int j = 0; j < 8; ++j) h[j] = 0.f;

    // hbuf[bd][pix][16ch bf16] = 32B/point; lane (wl,hi) owns 16B half hi
    int pix = ht * WW + wid * 32 + wl;
    char* hb0 = hbuf + ((size_t)b * BD * PLANE + pix) * 32 + hi * 16;

    // gates+scan for plane d given conv acc A; store bf16 h (16B, coalesced)
    auto tail = [&](const f32x16& A, int d) {
        union { uint4 u4; unsigned u[4]; } bx;
        #pragma unroll
        for (int r = 0; r < 8; ++r) {
            float z = tanh_fast(A[r]);
            float f = sigmoid_fast(A[r + 8]);
            h[r] = z + f * (h[r] - z);          // f*h + (1-f)*z
        }
        #pragma unroll
        for (int q = 0; q < 4; ++q)
            bx.u[q] = pack_bf2(h[2 * q], h[2 * q + 1]);
        *(uint4*)(hb0 + (size_t)d * (PLANE * 32)) = bx.u4;
    };

    int d0  = rev ? (BD - 1) : 0;
    int sgn = rev ? -1 : 1;
    int oobq = rev ? -1 : BD;

    stage(d0 & 3, d0);
    stage((d0 + sgn) & 3, d0 + sgn);
    zero_slot((d0 - sgn) & 3);
    __syncthreads();

    f32x16 accP;
    {
        int q = d0 + 2 * sgn;
        if (q >= 0 && q < BD) stage(q & 3, q);
        accP = convd(d0);
        __syncthreads();
    }

    #pragma unroll 1
    for (int i = 1; i < BD; ++i) {
        int d = d0 + sgn * i;
        int q = d + 2 * sgn;
        if (q >= 0 && q < BD) stage(q & 3, q);
        else if (q == oobq)   zero_slot(q & 3);

        f32x16 acc = convd(d);      // 27 MFMAs — independent of tail below
        tail(accP, d - sgn);        // gates/scan for previous d: interleaves
        accP = acc;

        __syncthreads();
    }
    tail(accP, d0 + sgn * (BD - 1));
}

// ---------------------------------------------------------------------------
// Kernel C: MLP via MFMA at full parallelism (63488 waves). B-frag = one 16B
// hbuf load (element e = channel k(e,hi) — matches kernel B's pack order and
// wtab2's shared k-map). Proven structure from round 6.
// ---------------------------------------------------------------------------
__global__ __launch_bounds__(256)
void mlp_mfma_kernel(const char* __restrict__ hbuf,
                     const ushort* __restrict__ wtab2,
                     float* __restrict__ out)
{
    int lane = threadIdx.x & 63;
    int wid  = threadIdx.x >> 6;
    int p    = lane & 31;
    int hi   = lane >> 5;

    size_t tile = (size_t)blockIdx.x * 4 + wid;
    size_t ptg  = tile * 32 + p;

    const bf16x8* W = (const bf16x8*)wtab2;
    bf16x8 af1  = W[lane];
    bf16x8 af2a = W[64 + lane];
    bf16x8 af2b = W[128 + lane];
    bf16x8 af3  = W[192 + lane];
    bf16x8 bx   = *(const bf16x8*)(hbuf + ptg * 32 + hi * 16);

    f32x16 zacc;
    #pragma unroll
    for (int r = 0; r < 16; ++r) zacc[r] = 0.f;

    f32x16 a1 = __builtin_amdgcn_mfma_f32_32x32x16_bf16(af1, bx, zacc, 0, 0, 0);
    f32x16 a3 = __builtin_amdgcn_mfma_f32_32x32x16_bf16(af3, bx, zacc, 0, 0, 0);

    union { bf16x8 v; unsigned u[4]; } b2a, b2b;
    #pragma unroll
    for (int q = 0; q < 4; ++q) {
        b2a.u[q] = pack_bf2(gelu_as(a1[2 * q]),     gelu_as(a1[2 * q + 1]));
        b2b.u[q] = pack_bf2(gelu_as(a1[8 + 2 * q]), gelu_as(a1[8 + 2 * q + 1]));
    }

    f32x16 a2 = __builtin_amdgcn_mfma_f32_32x32x16_bf16(af2a, b2a.v, zacc, 0, 0, 0);
    a2 = __builtin_amdgcn_mfma_f32_32x32x16_bf16(af2b, b2b.v, a2, 0, 0, 0);

    int bd  = (int)(ptg >> 14);
    int pix = (int)(ptg & 16383);
    int b   = bd / BD;
    int d   = bd % BD;
    float* obase = out + (size_t)b * HC * CH_STRIDE + (size_t)d * PLANE + pix;

    #pragma unroll
    for (int r = 0; r < 8; ++r) {
        int c = (r & 3) + 8 * (r >> 2) + 4 * hi;
        float y = a2[r] + a3[r] * sigmoid_fast(a3[r + 8]);
        obase[(size_t)c * CH_STRIDE] = y;
    }
}

extern "C" void kernel_launch(void* const* d_in, const int* in_sizes, int n_in,
                              void* d_out, int out_size, void* d_ws, size_t ws_size,
                              hipStream_t stream)
{
    const float* inp = (const float*)d_in[0];
    const float* cw  = (const float*)d_in[1];
    const float* w1  = (const float*)d_in[2];
    const float* w2  = (const float*)d_in[3];
    const float* w3  = (const float*)d_in[4];
    const int*   rev = (const int*)d_in[5];

    ushort* wtab  = (ushort*)d_ws;                    // [0, 27648)
    ushort* wtab2 = (ushort*)((char*)d_ws + 27648);   // [27648, 31744)
    char*   xT    = (char*)d_ws + 32768;              // 65,011,712 B
    char*   hbuf  = (char*)d_ws + 32768 + (size_t)4 * BD * 128 * 4096;  // 65 MB

    // 7936 xprep blocks + 62 weight-prep blocks, one launch
    xprep_kernel<<<dim3(7998), dim3(256), 0, stream>>>(
        inp, xT, cw, w1, w2, w3, wtab, wtab2);

    // conv+scan: 4b x 128ht = 512 blocks, persistent over all 31 d
    qrnn_convscan<<<dim3(512), dim3(256), 0, stream>>>(
        xT, wtab, hbuf, rev);

    // MLP: 2,031,616 points / 128 per block = 15872 blocks
    mlp_mfma_kernel<<<dim3(15872), dim3(256), 0, stream>>>(
        hbuf, wtab2, (float*)d_out);
}

// Round 13
// 148.580 us; speedup vs baseline: 1.0049x; 1.0049x over previous
//
#include <hip/hip_runtime.h>
#include <hip/hip_fp16.h>

#define HC 16
#define CIN 16
#define BD 31
#define HH 128
#define WW 128
#define PLANE (HH*WW)           // 16384
#define CH_STRIDE (BD*PLANE)    // 507904

typedef __attribute__((ext_vector_type(8))) short bf16x8;   // 8 bf16 = 4 VGPR
typedef __attribute__((ext_vector_type(16))) float f32x16;  // MFMA 32x32 acc

__device__ __forceinline__ float sigmoid_fast(float x) {
    return __builtin_amdgcn_rcpf(1.0f + __expf(-x));
}
__device__ __forceinline__ float tanh_fast(float x) {
    return fmaf(2.0f, __builtin_amdgcn_rcpf(1.0f + __expf(-2.0f * x)), -1.0f);
}
__device__ __forceinline__ ushort f2bf(float f) {   // RNE float->bf16 (prep paths)
    unsigned u = __float_as_uint(f);
    u = (u + 0x7fffu + ((u >> 16) & 1u)) >> 16;
    return (ushort)u;
}
// packed f32x2 -> bf16x2 via HW cvt_pk (no builtin on gfx950 — inline asm, T12)
__device__ __forceinline__ unsigned pack_bf2(float lo, float hi) {
    unsigned r;
    asm("v_cvt_pk_bf16_f32 %0, %1, %2" : "=v"(r) : "v"(lo), "v"(hi));
    return r;
}
// exact-gelu via Abramowitz-Stegun 7.1.26 erf (|eps|<=1.5e-7)
__device__ __forceinline__ float gelu_as(float s) {
    float z  = 0.70710678118f * s;
    float az = fabsf(z);
    float t  = __builtin_amdgcn_rcpf(fmaf(0.3275911f, az, 1.0f));
    float p  = t * (0.254829592f + t * (-0.284496736f + t * (1.421413741f
             + t * (-1.453152027f + t * 1.061405429f))));
    float e  = __expf(-z * z);
    float er = copysignf(1.0f - p * e, z);
    return 0.5f * s * (1.0f + er);
}

// ---------------------------------------------------------------------------
// xprep + weight prep in ONE launch (unchanged from round 12).
// ---------------------------------------------------------------------------
__global__ __launch_bounds__(256)
void xprep_kernel(const float* __restrict__ inp, char* __restrict__ xT,
                  const float* __restrict__ cw,
                  const float* __restrict__ w1,
                  const float* __restrict__ w2,
                  const float* __restrict__ w3,
                  ushort* __restrict__ wtab, ushort* __restrict__ wtab2)
{
    if (blockIdx.x >= 7936) {                 // weight-prep blocks
        int idx = (blockIdx.x - 7936) * 256 + threadIdx.x;
        if (idx < 13824) {
            int j    = idx & 7;
            int lane = (idx >> 3) & 63;
            int t    = (idx >> 9) % 9;
            int kd   = (idx >> 9) / 9;
            int co = lane & 31;
            int ci = 8 * (lane >> 5) + j;
            int kh = t / 3, kw = t % 3;
            wtab[idx] = f2bf(cw[(co * CIN + ci) * 27 + kd * 9 + kh * 3 + kw]);
            return;
        }
        idx -= 13824;
        if (idx >= 2048) return;
        int e    = idx & 7;
        int lane = (idx >> 3) & 63;
        int tbl  = idx >> 9;
        int m  = lane & 31;
        int hi = lane >> 5;
        int k  = (e & 3) + 8 * (e >> 2) + 4 * hi;   // shared k-permutation
        float v = 0.f;
        if (tbl == 0)      v = w1[k * 32 + m];
        else if (tbl == 3) v = w3[k * 32 + m];
        else {
            int mf = tbl - 1;
            if (m < 16) v = w2[(k + 16 * mf) * 16 + m];
        }
        wtab2[idx] = f2bf(v);
        return;
    }

    __shared__ float tile[16][256];
    int t  = threadIdx.x;
    int hp = blockIdx.x & 63;
    int g  = blockIdx.x >> 6;
    int d  = g % BD;
    int b  = g / BD;

    size_t src = (size_t)b * CIN * CH_STRIDE + (size_t)d * PLANE + hp * 256;
    #pragma unroll
    for (int c = 0; c < 16; ++c)
        tile[c][t] = inp[src + (size_t)c * CH_STRIDE + t];
    __syncthreads();

    int w  = t & 127;
    int rr = t >> 7;
    char* rowp = xT + (((size_t)(b * BD + d) * 128) + hp * 2 + rr) * 4096;
    #pragma unroll
    for (int q = 0; q < 2; ++q) {
        uint4 pk;
        pk.x = (unsigned)f2bf(tile[q*8+0][t]) | ((unsigned)f2bf(tile[q*8+1][t]) << 16);
        pk.y = (unsigned)f2bf(tile[q*8+2][t]) | ((unsigned)f2bf(tile[q*8+3][t]) << 16);
        pk.z = (unsigned)f2bf(tile[q*8+4][t]) | ((unsigned)f2bf(tile[q*8+5][t]) << 16);
        pk.w = (unsigned)f2bf(tile[q*8+6][t]) | ((unsigned)f2bf(tile[q*8+7][t]) << 16);
        unsigned off = ((unsigned)((w + 1) * 32 + q * 16) ^ (((unsigned)(w + 1) & 0xE) << 3)) - 32;
        *(uint4*)(rowp + off) = pk;
    }
}

// ---------------------------------------------------------------------------
// Kernel B: conv+scan, plane-at-a-time with 3 ROTATING ACCUMULATORS.
// Each plane p is read ONCE (9 B-frags, shared) and contributes 9 MFMAs to
// each of 3 concurrent output accumulators (outputs p-sgn, p, p+sgn) —
// breaking the old 27-deep serial MFMA chain into 3 independent 9-chains and
// cutting LDS reads 3x. kd->A-frag assignment resolved at load (afA/afB/afC)
// to keep indices compile-time (no scratch, rule #20). Rotation is positional
// via a 3x-unrolled loop body. OOB planes simply aren't processed (= SAME pad).
// ---------------------------------------------------------------------------
#define SLOT_B (3 * 4224)       // 12672 B per plane slot

__device__ __forceinline__ void gload_lds16(const void* g, void* l) {
    __builtin_amdgcn_global_load_lds(
        (const __attribute__((address_space(1))) unsigned int*)g,
        (__attribute__((address_space(3))) unsigned int*)l, 16, 0, 0);
}

__global__ __launch_bounds__(256, 2)
void qrnn_convscan(const char* __restrict__ xT,
                   const ushort* __restrict__ wtab,
                   char* __restrict__ hbuf,
                   const int* __restrict__ rev_p)
{
    __shared__ __align__(16) char slab[4][SLOT_B];

    // grid 512 = 8 XCD x 64
    int p = blockIdx.x;
    int logical = (p & 7) * 64 + (p >> 3);
    int b  = logical >> 7;
    int ht = logical & 127;
    int rev = rev_p[0];
    int sgn = rev ? -1 : 1;
    int d0  = rev ? (BD - 1) : 0;

    int lane = threadIdx.x & 63;
    int wid  = threadIdx.x >> 6;
    int wl   = lane & 31;
    int hi   = lane >> 5;
    int cio  = hi * 16;

    // A-frag tables by role: completing acc gets kd=1+sgn, starting acc kd=1-sgn
    const bf16x8* wt = (const bf16x8*)wtab;
    int kdA = rev ? 0 : 2;
    int kdC = rev ? 2 : 0;
    bf16x8 afA[9], afB[9], afC[9];
    #pragma unroll
    for (int t = 0; t < 9; ++t) {
        afA[t] = wt[(kdA * 9 + t) * 64 + lane];
        afB[t] = wt[(9      + t) * 64 + lane];
        afC[t] = wt[(kdC * 9 + t) * 64 + lane];
    }

    unsigned bpo[3];
    #pragma unroll
    for (int dwn = 0; dwn < 3; ++dwn) {
        unsigned wc = (unsigned)(wl + dwn);
        bpo[dwn] = (unsigned)(wid * 1024) + ((wc * 32 + cio) ^ ((wc & 0xE) << 3));
    }

    // zero w-edge columns of all 4 slots (interior is always overwritten)
    for (int i = threadIdx.x; i < 4 * 3 * 32; i += 256) {
        int s = i / 96;
        int r = (i / 32) % 3;
        int k = i & 31;
        int off = (k < 8) ? (k * 4) : (4128 + (k - 8) * 4);
        *(int*)(slab[s] + r * 4224 + off) = 0;
    }

    auto stage = [&](int plane) {
        const char* pl = xT + ((size_t)(b * BD + plane) * 128) * 4096;
        char* sb = slab[plane & 3];
        for (int c = wid; c < 12; c += 4) {
            int rr = c >> 2, ch = c & 3;
            int h = ht - 1 + rr;
            char* dst = sb + rr * 4224 + 32 + ch * 1024;
            if ((unsigned)h < (unsigned)HH)
                gload_lds16(pl + (size_t)h * 4096 + ch * 1024 + lane * 16, dst);
            else
                *(uint4*)(dst + lane * 16) = uint4{0, 0, 0, 0};
        }
    };

    f32x16 zacc;
    #pragma unroll
    for (int r = 0; r < 16; ++r) zacc[r] = 0.f;

    float h[8];
    #pragma unroll
    for (int j = 0; j < 8; ++j) h[j] = 0.f;

    // hbuf[bd][pix][16ch bf16] = 32B/point; lane (wl,hi) owns 16B half hi
    int pix = ht * WW + wid * 32 + wl;
    char* hb0 = hbuf + ((size_t)b * BD * PLANE + pix) * 32 + hi * 16;

    auto tail = [&](const f32x16& A, int d) {
        union { uint4 u4; unsigned u[4]; } bx;
        #pragma unroll
        for (int r = 0; r < 8; ++r) {
            float z = tanh_fast(A[r]);
            float f = sigmoid_fast(A[r + 8]);
            h[r] = z + f * (h[r] - z);          // f*h + (1-f)*z
        }
        #pragma unroll
        for (int q = 0; q < 4; ++q)
            bx.u[q] = pack_bf2(h[2 * q], h[2 * q + 1]);
        *(uint4*)(hb0 + (size_t)d * (PLANE * 32)) = bx.u4;
    };

    // one plane step: X completes (output q-sgn), Y mid, Z starts (output q+sgn)
    auto step = [&](int i, f32x16& X, f32x16& Y, f32x16& Z) {
        if (i > BD) return;                        // uniform guard
        int q = d0 + sgn * i;                      // plane index (OOB at i==BD)
        if (i + 2 < BD) stage(d0 + sgn * (i + 2)); // 2-ahead prefetch
        if (i < BD) {
            const char* sb = slab[q & 3];
            #pragma unroll
            for (int t = 0; t < 9; ++t) {
                bf16x8 B = *(const bf16x8*)(sb + (t / 3) * 4224 + bpo[t % 3]);
                X = __builtin_amdgcn_mfma_f32_32x32x16_bf16(afA[t], B, X, 0, 0, 0);
                Y = __builtin_amdgcn_mfma_f32_32x32x16_bf16(afB[t], B, Y, 0, 0, 0);
                Z = __builtin_amdgcn_mfma_f32_32x32x16_bf16(afC[t], B, Z, 0, 0, 0);
            }
        }
        if (i >= 1) tail(X, q - sgn);              // output q-sgn now complete
        X = zacc;                                  // X becomes next step's Z
        __syncthreads();                           // staged plane landed
    };

    // prologue: planes for steps 0 and 1 in flight
    stage(d0);
    stage(d0 + sgn);
    __syncthreads();

    f32x16 accA = zacc, accB = zacc, accC = zacc;
    #pragma unroll 1
    for (int i = 0; i <= BD; i += 3) {             // 32 logical steps (0..31)
        step(i,     accA, accB, accC);
        step(i + 1, accB, accC, accA);
        step(i + 2, accC, accA, accB);
    }
}

// ---------------------------------------------------------------------------
// Kernel C: MLP via MFMA at full parallelism (unchanged from round 12).
// ---------------------------------------------------------------------------
__global__ __launch_bounds__(256)
void mlp_mfma_kernel(const char* __restrict__ hbuf,
                     const ushort* __restrict__ wtab2,
                     float* __restrict__ out)
{
    int lane = threadIdx.x & 63;
    int wid  = threadIdx.x >> 6;
    int p    = lane & 31;
    int hi   = lane >> 5;

    size_t tile = (size_t)blockIdx.x * 4 + wid;
    size_t ptg  = tile * 32 + p;

    const bf16x8* W = (const bf16x8*)wtab2;
    bf16x8 af1  = W[lane];
    bf16x8 af2a = W[64 + lane];
    bf16x8 af2b = W[128 + lane];
    bf16x8 af3  = W[192 + lane];
    bf16x8 bx   = *(const bf16x8*)(hbuf + ptg * 32 + hi * 16);

    f32x16 zacc;
    #pragma unroll
    for (int r = 0; r < 16; ++r) zacc[r] = 0.f;

    f32x16 a1 = __builtin_amdgcn_mfma_f32_32x32x16_bf16(af1, bx, zacc, 0, 0, 0);
    f32x16 a3 = __builtin_amdgcn_mfma_f32_32x32x16_bf16(af3, bx, zacc, 0, 0, 0);

    union { bf16x8 v; unsigned u[4]; } b2a, b2b;
    #pragma unroll
    for (int q = 0; q < 4; ++q) {
        b2a.u[q] = pack_bf2(gelu_as(a1[2 * q]),     gelu_as(a1[2 * q + 1]));
        b2b.u[q] = pack_bf2(gelu_as(a1[8 + 2 * q]), gelu_as(a1[8 + 2 * q + 1]));
    }

    f32x16 a2 = __builtin_amdgcn_mfma_f32_32x32x16_bf16(af2a, b2a.v, zacc, 0, 0, 0);
    a2 = __builtin_amdgcn_mfma_f32_32x32x16_bf16(af2b, b2b.v, a2, 0, 0, 0);

    int bd  = (int)(ptg >> 14);
    int pix = (int)(ptg & 16383);
    int b   = bd / BD;
    int d   = bd % BD;
    float* obase = out + (size_t)b * HC * CH_STRIDE + (size_t)d * PLANE + pix;

    #pragma unroll
    for (int r = 0; r < 8; ++r) {
        int c = (r & 3) + 8 * (r >> 2) + 4 * hi;
        float y = a2[r] + a3[r] * sigmoid_fast(a3[r + 8]);
        obase[(size_t)c * CH_STRIDE] = y;
    }
}

extern "C" void kernel_launch(void* const* d_in, const int* in_sizes, int n_in,
                              void* d_out, int out_size, void* d_ws, size_t ws_size,
                              hipStream_t stream)
{
    const float* inp = (const float*)d_in[0];
    const float* cw  = (const float*)d_in[1];
    const float* w1  = (const float*)d_in[2];
    const float* w2  = (const float*)d_in[3];
    const float* w3  = (const float*)d_in[4];
    const int*   rev = (const int*)d_in[5];

    ushort* wtab  = (ushort*)d_ws;                    // [0, 27648)
    ushort* wtab2 = (ushort*)((char*)d_ws + 27648);   // [27648, 31744)
    char*   xT    = (char*)d_ws + 32768;              // 65,011,712 B
    char*   hbuf  = (char*)d_ws + 32768 + (size_t)4 * BD * 128 * 4096;  // 65 MB

    // 7936 xprep blocks + 62 weight-prep blocks, one launch
    xprep_kernel<<<dim3(7998), dim3(256), 0, stream>>>(
        inp, xT, cw, w1, w2, w3, wtab, wtab2);

    // conv+scan: 4b x 128ht = 512 blocks, persistent over all 31 d
    qrnn_convscan<<<dim3(512), dim3(256), 0, stream>>>(
        xT, wtab, hbuf, rev);

    // MLP: 2,031,616 points / 128 per block = 15872 blocks
    mlp_mfma_kernel<<<dim3(15872), dim3(256), 0, stream>>>(
        hbuf, wtab2, (float*)d_out);
}

// Round 14
// 135.226 us; speedup vs baseline: 1.1041x; 1.0988x over previous
//
#include <hip/hip_runtime.h>
#include <hip/hip_fp16.h>

#define HC 16
#define CIN 16
#define BD 31
#define HH 128
#define WW 128
#define PLANE (HH*WW)           // 16384
#define CH_STRIDE (BD*PLANE)    // 507904

typedef __attribute__((ext_vector_type(8))) short bf16x8;   // 8 bf16 = 4 VGPR
typedef __attribute__((ext_vector_type(16))) float f32x16;  // MFMA 32x32 acc

__device__ __forceinline__ float sigmoid_fast(float x) {
    return __builtin_amdgcn_rcpf(1.0f + __expf(-x));
}
__device__ __forceinline__ ushort f2bf(float f) {   // RNE float->bf16 (prep paths)
    unsigned u = __float_as_uint(f);
    u = (u + 0x7fffu + ((u >> 16) & 1u)) >> 16;
    return (ushort)u;
}
// packed f32x2 -> bf16x2 via HW cvt_pk (no builtin on gfx950 — inline asm, T12)
__device__ __forceinline__ unsigned pack_bf2(float lo, float hi) {
    unsigned r;
    asm("v_cvt_pk_bf16_f32 %0, %1, %2" : "=v"(r) : "v"(lo), "v"(hi));
    return r;
}
// paired sigmoids: sig(a), sig(b) with ONE rcp (TRANS is the bottleneck pipe:
// v_exp/v_rcp are quarter-rate on the VALU — 16 cyc each at wave64).
__device__ __forceinline__ float2 sigmoid2(float a, float b) {
    float ea = __expf(-a);
    float eb = __expf(-b);
    float pa = 1.0f + ea, pb = 1.0f + eb;
    float r  = __builtin_amdgcn_rcpf(pa * pb);
    return make_float2(pb * r, pa * r);      // 1/pa, 1/pb
}
// paired tanh-form gelus (|err vs exact-erf gelu| <~5e-4), shared rcp:
// gelu(x) = x * sigma(1.5957691*(x + 0.044715*x^3))
__device__ __forceinline__ float2 gelu2(float x, float y) {
    float ux = fmaf(0.044715f * x, x * x, x);
    float uy = fmaf(0.044715f * y, y * y, y);
    float ex = __expf(-1.5957691f * ux);
    float ey = __expf(-1.5957691f * uy);
    float px = 1.0f + ex, py = 1.0f + ey;
    float r  = __builtin_amdgcn_rcpf(px * py);
    return make_float2(x * py * r, y * px * r);
}

// ---------------------------------------------------------------------------
// Merged weight prep (round 9/11 layout, unchanged).
// ---------------------------------------------------------------------------
__global__ void wprep_all(const float* __restrict__ cw,
                          const float* __restrict__ w1,
                          const float* __restrict__ w2,
                          const float* __restrict__ w3,
                          ushort* __restrict__ wtab,
                          ushort* __restrict__ wtab2)
{
    int idx = blockIdx.x * 256 + threadIdx.x;
    if (idx < 13824) {
        int j    = idx & 7;
        int lane = (idx >> 3) & 63;
        int t    = (idx >> 9) % 9;
        int kd   = (idx >> 9) / 9;
        int co = lane & 31;
        int ci = 8 * (lane >> 5) + j;
        int kh = t / 3, kw = t % 3;
        wtab[idx] = f2bf(cw[(co * CIN + ci) * 27 + kd * 9 + kh * 3 + kw]);
        return;
    }
    idx -= 13824;
    if (idx >= 2048) return;
    int e    = idx & 7;
    int lane = (idx >> 3) & 63;
    int tbl  = idx >> 9;
    int m  = lane & 31;
    int hi = lane >> 5;
    int k  = (e & 3) + 8 * (e >> 2) + 4 * hi;   // shared k-permutation
    float v = 0.f;
    if (tbl == 0)      v = w1[k * 32 + m];
    else if (tbl == 3) v = w3[k * 32 + m];
    else {
        int mf = tbl - 1;
        if (m < 16) v = w2[(k + 16 * mf) * 16 + m];
    }
    wtab2[idx] = f2bf(v);
}

// ---------------------------------------------------------------------------
// xprep (unchanged): fp32 -> bf16 rows xT[b][d][h][4096B], swizzle pre-baked.
// ---------------------------------------------------------------------------
__global__ __launch_bounds__(256)
void xprep_kernel(const float* __restrict__ inp, char* __restrict__ xT)
{
    __shared__ float tile[16][256];
    int t  = threadIdx.x;
    int hp = blockIdx.x & 63;
    int g  = blockIdx.x >> 6;
    int d  = g % BD;
    int b  = g / BD;

    size_t src = (size_t)b * CIN * CH_STRIDE + (size_t)d * PLANE + hp * 256;
    #pragma unroll
    for (int c = 0; c < 16; ++c)
        tile[c][t] = inp[src + (size_t)c * CH_STRIDE + t];
    __syncthreads();

    int w  = t & 127;
    int rr = t >> 7;
    char* rowp = xT + (((size_t)(b * BD + d) * 128) + hp * 2 + rr) * 4096;
    #pragma unroll
    for (int q = 0; q < 2; ++q) {
        uint4 pk;
        pk.x = (unsigned)f2bf(tile[q*8+0][t]) | ((unsigned)f2bf(tile[q*8+1][t]) << 16);
        pk.y = (unsigned)f2bf(tile[q*8+2][t]) | ((unsigned)f2bf(tile[q*8+3][t]) << 16);
        pk.z = (unsigned)f2bf(tile[q*8+4][t]) | ((unsigned)f2bf(tile[q*8+5][t]) << 16);
        pk.w = (unsigned)f2bf(tile[q*8+6][t]) | ((unsigned)f2bf(tile[q*8+7][t]) << 16);
        unsigned off = ((unsigned)((w + 1) * 32 + q * 16) ^ (((unsigned)(w + 1) & 0xE) << 3)) - 32;
        *(uint4*)(rowp + off) = pk;
    }
}

// ---------------------------------------------------------------------------
// FUSED conv+scan+MLP (round-11 structure, the measured-best back half) with
// the TRANS-reduced tail: paired-rcp gates, tanh-form paired gelu, paired
// output sigmoids — 80 -> 56 TRANS ops/lane/d on the quarter-rate pipe.
// ---------------------------------------------------------------------------
#define SLOT_B (3 * 4224)       // 12672 B per plane slot

__device__ __forceinline__ void gload_lds16(const void* g, void* l) {
    __builtin_amdgcn_global_load_lds(
        (const __attribute__((address_space(1))) unsigned int*)g,
        (__attribute__((address_space(3))) unsigned int*)l, 16, 0, 0);
}

__global__ __launch_bounds__(256, 2)
void qrnn_fused(const char* __restrict__ xT,
                const ushort* __restrict__ wtab,
                const ushort* __restrict__ wtab2,
                float* __restrict__ out,
                const int* __restrict__ rev_p)
{
    __shared__ __align__(16) char slab[4][SLOT_B];

    // grid 512 = 8 XCD x 64
    int p = blockIdx.x;
    int logical = (p & 7) * 64 + (p >> 3);
    int b  = logical >> 7;
    int ht = logical & 127;
    int rev = rev_p[0];

    int lane = threadIdx.x & 63;
    int wid  = threadIdx.x >> 6;
    int wl   = lane & 31;
    int hi   = lane >> 5;
    int cio  = hi * 16;

    const bf16x8* wt = (const bf16x8*)wtab;
    bf16x8 af[27];
    #pragma unroll
    for (int t = 0; t < 27; ++t) af[t] = wt[t * 64 + lane];

    const bf16x8* W2 = (const bf16x8*)wtab2;
    bf16x8 af1  = W2[lane];
    bf16x8 af2a = W2[64 + lane];
    bf16x8 af2b = W2[128 + lane];
    bf16x8 af3  = W2[192 + lane];

    unsigned bpo[3];
    #pragma unroll
    for (int dwn = 0; dwn < 3; ++dwn) {
        unsigned wc = (unsigned)(wl + dwn);
        bpo[dwn] = (unsigned)(wid * 1024) + ((wc * 32 + cio) ^ ((wc & 0xE) << 3));
    }

    for (int i = threadIdx.x; i < 4 * 3 * 32; i += 256) {
        int s = i / 96;
        int r = (i / 32) % 3;
        int k = i & 31;
        int off = (k < 8) ? (k * 4) : (4128 + (k - 8) * 4);
        *(int*)(slab[s] + r * 4224 + off) = 0;
    }

    auto zero_slot = [&](int s) {
        for (int i = threadIdx.x; i < 768; i += 256) {
            int r = i >> 8;
            int k = i & 255;
            *(uint4*)(slab[s] + r * 4224 + 32 + k * 16) = uint4{0, 0, 0, 0};
        }
    };

    auto stage = [&](int s, int plane) {
        const char* pl = xT + ((size_t)(b * BD + plane) * 128) * 4096;
        for (int c = wid; c < 12; c += 4) {
            int rr = c >> 2, ch = c & 3;
            int h = ht - 1 + rr;
            char* dst = slab[s] + rr * 4224 + 32 + ch * 1024;
            if ((unsigned)h < (unsigned)HH)
                gload_lds16(pl + (size_t)h * 4096 + ch * 1024 + lane * 16, dst);
            else
                *(uint4*)(dst + lane * 16) = uint4{0, 0, 0, 0};
        }
    };

    f32x16 zacc;
    #pragma unroll
    for (int r = 0; r < 16; ++r) zacc[r] = 0.f;

    auto convd = [&](int d) -> f32x16 {
        f32x16 A = zacc;
        #pragma unroll
        for (int kd = 0; kd < 3; ++kd) {
            const char* sb = slab[(d - 1 + kd) & 3];   // OOB slots hold zeros
            #pragma unroll
            for (int t = 0; t < 9; ++t) {
                bf16x8 bfr = *(const bf16x8*)(sb + (t / 3) * 4224 + bpo[t % 3]);
                A = __builtin_amdgcn_mfma_f32_32x32x16_bf16(af[kd * 9 + t], bfr, A, 0, 0, 0);
            }
        }
        return A;
    };

    float h[8];
    #pragma unroll
    for (int j = 0; j < 8; ++j) h[j] = 0.f;

    float* obase = out + (size_t)b * HC * CH_STRIDE + ht * WW + wid * 32 + wl;

    // tail: gates -> scan -> MLP -> store for plane d, given conv acc A.
    auto tail = [&](const f32x16& A, int d) {
        union { bf16x8 v; unsigned u[4]; } bx;
        #pragma unroll
        for (int r = 0; r < 8; ++r) {
            // z = tanh(a) = 2*sig(2a)-1, f = sig(b); one shared rcp per pair
            float2 s = sigmoid2(2.0f * A[r], A[r + 8]);
            float z = fmaf(2.0f, s.x, -1.0f);
            float f = s.y;
            h[r] = z + f * (h[r] - z);          // f*h + (1-f)*z
        }
        #pragma unroll
        for (int q = 0; q < 4; ++q)
            bx.u[q] = pack_bf2(h[2 * q], h[2 * q + 1]);

        f32x16 a1 = __builtin_amdgcn_mfma_f32_32x32x16_bf16(af1, bx.v, zacc, 0, 0, 0);
        f32x16 a3 = __builtin_amdgcn_mfma_f32_32x32x16_bf16(af3, bx.v, zacc, 0, 0, 0);

        union { bf16x8 v; unsigned u[4]; } b2a, b2b;
        #pragma unroll
        for (int q = 0; q < 4; ++q) {
            float2 ga = gelu2(a1[2 * q],     a1[2 * q + 1]);
            float2 gb = gelu2(a1[8 + 2 * q], a1[8 + 2 * q + 1]);
            b2a.u[q] = pack_bf2(ga.x, ga.y);
            b2b.u[q] = pack_bf2(gb.x, gb.y);
        }
        f32x16 a2 = __builtin_amdgcn_mfma_f32_32x32x16_bf16(af2a, b2a.v, zacc, 0, 0, 0);
        a2 = __builtin_amdgcn_mfma_f32_32x32x16_bf16(af2b, b2b.v, a2, 0, 0, 0);

        float* ob = obase + (size_t)d * PLANE;
        #pragma unroll
        for (int q = 0; q < 4; ++q) {
            float2 s = sigmoid2(a3[8 + 2 * q], a3[9 + 2 * q]);
            int c0 = (2 * q     & 3) + 8 * (2 * q     >> 2) + 4 * hi;
            int c1 = (2 * q + 1 & 3) + 8 * (2 * q + 1 >> 2) + 4 * hi;
            ob[(size_t)c0 * CH_STRIDE] = fmaf(a3[2 * q],     s.x, a2[2 * q]);
            ob[(size_t)c1 * CH_STRIDE] = fmaf(a3[2 * q + 1], s.y, a2[2 * q + 1]);
        }
    };

    int d0  = rev ? (BD - 1) : 0;
    int sgn = rev ? -1 : 1;
    int oobq = rev ? -1 : BD;

    stage(d0 & 3, d0);
    stage((d0 + sgn) & 3, d0 + sgn);
    zero_slot((d0 - sgn) & 3);
    __syncthreads();

    f32x16 accP;
    {
        int q = d0 + 2 * sgn;
        if (q >= 0 && q < BD) stage(q & 3, q);
        accP = convd(d0);
        __syncthreads();
    }

    #pragma unroll 1
    for (int i = 1; i < BD; ++i) {
        int d = d0 + sgn * i;
        int q = d + 2 * sgn;
        if (q >= 0 && q < BD) stage(q & 3, q);
        else if (q == oobq)   zero_slot(q & 3);

        f32x16 acc = convd(d);      // 27 MFMAs — independent of tail below
        tail(accP, d - sgn);        // VALU/TRANS chain for previous d
        accP = acc;

        __syncthreads();
    }
    tail(accP, d0 + sgn * (BD - 1));
}

extern "C" void kernel_launch(void* const* d_in, const int* in_sizes, int n_in,
                              void* d_out, int out_size, void* d_ws, size_t ws_size,
                              hipStream_t stream)
{
    const float* inp = (const float*)d_in[0];
    const float* cw  = (const float*)d_in[1];
    const float* w1  = (const float*)d_in[2];
    const float* w2  = (const float*)d_in[3];
    const float* w3  = (const float*)d_in[4];
    const int*   rev = (const int*)d_in[5];

    ushort* wtab  = (ushort*)d_ws;                    // [0, 27648)
    ushort* wtab2 = (ushort*)((char*)d_ws + 27648);   // [27648, 31744)
    char*   xT    = (char*)d_ws + 32768;              // 65,011,712 B

    wprep_all<<<dim3(62), dim3(256), 0, stream>>>(cw, w1, w2, w3, wtab, wtab2);

    xprep_kernel<<<dim3(7936), dim3(256), 0, stream>>>(inp, xT);

    // 4b x 128ht = 512 blocks (2 per CU), persistent over all 31 d
    qrnn_fused<<<dim3(512), dim3(256), 0, stream>>>(
        xT, wtab, wtab2, (float*)d_out, rev);
}

// Round 15
// 132.939 us; speedup vs baseline: 1.1231x; 1.0172x over previous
//
#include <hip/hip_runtime.h>
#include <hip/hip_fp16.h>

#define HC 16
#define CIN 16
#define BD 31
#define HH 128
#define WW 128
#define PLANE (HH*WW)           // 16384
#define CH_STRIDE (BD*PLANE)    // 507904

typedef __attribute__((ext_vector_type(8))) short bf16x8;   // 8 bf16 = 4 VGPR
typedef __attribute__((ext_vector_type(16))) float f32x16;  // MFMA 32x32 acc

__device__ __forceinline__ ushort f2bf(float f) {   // RNE float->bf16 (prep paths)
    unsigned u = __float_as_uint(f);
    u = (u + 0x7fffu + ((u >> 16) & 1u)) >> 16;
    return (ushort)u;
}
// packed f32x2 -> bf16x2 via HW cvt_pk (no builtin on gfx950 — inline asm, T12)
__device__ __forceinline__ unsigned pack_bf2(float lo, float hi) {
    unsigned r;
    asm("v_cvt_pk_bf16_f32 %0, %1, %2" : "=v"(r) : "v"(lo), "v"(hi));
    return r;
}
// paired sigmoids: sig(a), sig(b) with ONE rcp (TRANS is quarter-rate).
__device__ __forceinline__ float2 sigmoid2(float a, float b) {
    float ea = __expf(-a);
    float eb = __expf(-b);
    float pa = 1.0f + ea, pb = 1.0f + eb;
    float r  = __builtin_amdgcn_rcpf(pa * pb);
    return make_float2(pb * r, pa * r);      // 1/pa, 1/pb
}
// paired tanh-form gelus (|err vs exact-erf gelu| <~5e-4), shared rcp:
// gelu(x) = x * sigma(1.5957691*(x + 0.044715*x^3))
__device__ __forceinline__ float2 gelu2(float x, float y) {
    float ux = fmaf(0.044715f * x, x * x, x);
    float uy = fmaf(0.044715f * y, y * y, y);
    float ex = __expf(-1.5957691f * ux);
    float ey = __expf(-1.5957691f * uy);
    float px = 1.0f + ex, py = 1.0f + ey;
    float r  = __builtin_amdgcn_rcpf(px * py);
    return make_float2(x * py * r, y * px * r);
}

// ---------------------------------------------------------------------------
// Merged weight prep (unchanged).
// ---------------------------------------------------------------------------
__global__ void wprep_all(const float* __restrict__ cw,
                          const float* __restrict__ w1,
                          const float* __restrict__ w2,
                          const float* __restrict__ w3,
                          ushort* __restrict__ wtab,
                          ushort* __restrict__ wtab2)
{
    int idx = blockIdx.x * 256 + threadIdx.x;
    if (idx < 13824) {
        int j    = idx & 7;
        int lane = (idx >> 3) & 63;
        int t    = (idx >> 9) % 9;
        int kd   = (idx >> 9) / 9;
        int co = lane & 31;
        int ci = 8 * (lane >> 5) + j;
        int kh = t / 3, kw = t % 3;
        wtab[idx] = f2bf(cw[(co * CIN + ci) * 27 + kd * 9 + kh * 3 + kw]);
        return;
    }
    idx -= 13824;
    if (idx >= 2048) return;
    int e    = idx & 7;
    int lane = (idx >> 3) & 63;
    int tbl  = idx >> 9;
    int m  = lane & 31;
    int hi = lane >> 5;
    int k  = (e & 3) + 8 * (e >> 2) + 4 * hi;   // shared k-permutation
    float v = 0.f;
    if (tbl == 0)      v = w1[k * 32 + m];
    else if (tbl == 3) v = w3[k * 32 + m];
    else {
        int mf = tbl - 1;
        if (m < 16) v = w2[(k + 16 * mf) * 16 + m];
    }
    wtab2[idx] = f2bf(v);
}

// ---------------------------------------------------------------------------
// xprep (unchanged): fp32 -> bf16 rows xT[b][d][h][4096B], swizzle pre-baked.
// ---------------------------------------------------------------------------
__global__ __launch_bounds__(256)
void xprep_kernel(const float* __restrict__ inp, char* __restrict__ xT)
{
    __shared__ float tile[16][256];
    int t  = threadIdx.x;
    int hp = blockIdx.x & 63;
    int g  = blockIdx.x >> 6;
    int d  = g % BD;
    int b  = g / BD;

    size_t src = (size_t)b * CIN * CH_STRIDE + (size_t)d * PLANE + hp * 256;
    #pragma unroll
    for (int c = 0; c < 16; ++c)
        tile[c][t] = inp[src + (size_t)c * CH_STRIDE + t];
    __syncthreads();

    int w  = t & 127;
    int rr = t >> 7;
    char* rowp = xT + (((size_t)(b * BD + d) * 128) + hp * 2 + rr) * 4096;
    #pragma unroll
    for (int q = 0; q < 2; ++q) {
        uint4 pk;
        pk.x = (unsigned)f2bf(tile[q*8+0][t]) | ((unsigned)f2bf(tile[q*8+1][t]) << 16);
        pk.y = (unsigned)f2bf(tile[q*8+2][t]) | ((unsigned)f2bf(tile[q*8+3][t]) << 16);
        pk.z = (unsigned)f2bf(tile[q*8+4][t]) | ((unsigned)f2bf(tile[q*8+5][t]) << 16);
        pk.w = (unsigned)f2bf(tile[q*8+6][t]) | ((unsigned)f2bf(tile[q*8+7][t]) << 16);
        unsigned off = ((unsigned)((w + 1) * 32 + q * 16) ^ (((unsigned)(w + 1) & 0xE) << 3)) - 32;
        *(uint4*)(rowp + off) = pk;
    }
}

// ---------------------------------------------------------------------------
// FUSED conv+scan+MLP with 3 ROTATING ACCUMULATORS: each plane is read ONCE
// (9 B-frags) and feeds 9 MFMAs into each of 3 concurrent output accumulators
// (outputs q-sgn, q, q+sgn; kd-role A-frags afA/afB/afC resolved at load).
// Cuts the CU-shared LDS-read pipe 3x (27->9 b128/wave/d) and splits the
// 27-deep MFMA chain into 3 independent 9-chains. Tail = TRANS-reduced
// gates/scan/MLP (r14), fired when an accumulator completes.
// ---------------------------------------------------------------------------
#define SLOT_B (3 * 4224)       // 12672 B per plane slot

__device__ __forceinline__ void gload_lds16(const void* g, void* l) {
    __builtin_amdgcn_global_load_lds(
        (const __attribute__((address_space(1))) unsigned int*)g,
        (__attribute__((address_space(3))) unsigned int*)l, 16, 0, 0);
}

__global__ __launch_bounds__(256, 2)
void qrnn_fused(const char* __restrict__ xT,
                const ushort* __restrict__ wtab,
                const ushort* __restrict__ wtab2,
                float* __restrict__ out,
                const int* __restrict__ rev_p)
{
    __shared__ __align__(16) char slab[4][SLOT_B];

    // grid 512 = 8 XCD x 64
    int p = blockIdx.x;
    int logical = (p & 7) * 64 + (p >> 3);
    int b  = logical >> 7;
    int ht = logical & 127;
    int rev = rev_p[0];
    int sgn = rev ? -1 : 1;
    int d0  = rev ? (BD - 1) : 0;

    int lane = threadIdx.x & 63;
    int wid  = threadIdx.x >> 6;
    int wl   = lane & 31;
    int hi   = lane >> 5;
    int cio  = hi * 16;

    // A-frag role tables: plane q contributes to output q-sgn with kd=1+sgn
    // (afA, completing), output q with kd=1 (afB), output q+sgn with kd=1-sgn
    // (afC, starting). Verified in r13 (split form, passed).
    const bf16x8* wt = (const bf16x8*)wtab;
    int kdA = rev ? 0 : 2;
    int kdC = rev ? 2 : 0;
    bf16x8 afA[9], afB[9], afC[9];
    #pragma unroll
    for (int t = 0; t < 9; ++t) {
        afA[t] = wt[(kdA * 9 + t) * 64 + lane];
        afB[t] = wt[(9      + t) * 64 + lane];
        afC[t] = wt[(kdC * 9 + t) * 64 + lane];
    }

    const bf16x8* W2 = (const bf16x8*)wtab2;
    bf16x8 af1  = W2[lane];
    bf16x8 af2a = W2[64 + lane];
    bf16x8 af2b = W2[128 + lane];
    bf16x8 af3  = W2[192 + lane];

    unsigned bpo[3];
    #pragma unroll
    for (int dwn = 0; dwn < 3; ++dwn) {
        unsigned wc = (unsigned)(wl + dwn);
        bpo[dwn] = (unsigned)(wid * 1024) + ((wc * 32 + cio) ^ ((wc & 0xE) << 3));
    }

    // zero w-edge columns of all 4 slots (interior is always fully staged;
    // stage never touches the edges so these zeros persist across rotation)
    for (int i = threadIdx.x; i < 4 * 3 * 32; i += 256) {
        int s = i / 96;
        int r = (i / 32) % 3;
        int k = i & 31;
        int off = (k < 8) ? (k * 4) : (4128 + (k - 8) * 4);
        *(int*)(slab[s] + r * 4224 + off) = 0;
    }

    auto stage = [&](int plane) {
        const char* pl = xT + ((size_t)(b * BD + plane) * 128) * 4096;
        char* sb = slab[plane & 3];
        for (int c = wid; c < 12; c += 4) {
            int rr = c >> 2, ch = c & 3;
            int h = ht - 1 + rr;
            char* dst = sb + rr * 4224 + 32 + ch * 1024;
            if ((unsigned)h < (unsigned)HH)
                gload_lds16(pl + (size_t)h * 4096 + ch * 1024 + lane * 16, dst);
            else
                *(uint4*)(dst + lane * 16) = uint4{0, 0, 0, 0};
        }
    };

    f32x16 zacc;
    #pragma unroll
    for (int r = 0; r < 16; ++r) zacc[r] = 0.f;

    float h[8];
    #pragma unroll
    for (int j = 0; j < 8; ++j) h[j] = 0.f;

    float* obase = out + (size_t)b * HC * CH_STRIDE + ht * WW + wid * 32 + wl;

    // tail: gates -> scan -> MLP -> store for output plane d, given conv acc A.
    auto tail = [&](const f32x16& A, int d) {
        union { bf16x8 v; unsigned u[4]; } bx;
        #pragma unroll
        for (int r = 0; r < 8; ++r) {
            float2 s = sigmoid2(2.0f * A[r], A[r + 8]);
            float z = fmaf(2.0f, s.x, -1.0f);    // tanh via sigmoid
            float f = s.y;
            h[r] = z + f * (h[r] - z);           // f*h + (1-f)*z
        }
        #pragma unroll
        for (int q = 0; q < 4; ++q)
            bx.u[q] = pack_bf2(h[2 * q], h[2 * q + 1]);

        f32x16 a1 = __builtin_amdgcn_mfma_f32_32x32x16_bf16(af1, bx.v, zacc, 0, 0, 0);
        f32x16 a3 = __builtin_amdgcn_mfma_f32_32x32x16_bf16(af3, bx.v, zacc, 0, 0, 0);

        union { bf16x8 v; unsigned u[4]; } b2a, b2b;
        #pragma unroll
        for (int q = 0; q < 4; ++q) {
            float2 ga = gelu2(a1[2 * q],     a1[2 * q + 1]);
            float2 gb = gelu2(a1[8 + 2 * q], a1[8 + 2 * q + 1]);
            b2a.u[q] = pack_bf2(ga.x, ga.y);
            b2b.u[q] = pack_bf2(gb.x, gb.y);
        }
        f32x16 a2 = __builtin_amdgcn_mfma_f32_32x32x16_bf16(af2a, b2a.v, zacc, 0, 0, 0);
        a2 = __builtin_amdgcn_mfma_f32_32x32x16_bf16(af2b, b2b.v, a2, 0, 0, 0);

        float* ob = obase + (size_t)d * PLANE;
        #pragma unroll
        for (int q = 0; q < 4; ++q) {
            float2 s = sigmoid2(a3[8 + 2 * q], a3[9 + 2 * q]);
            int c0 = (2 * q     & 3) + 8 * (2 * q     >> 2) + 4 * hi;
            int c1 = (2 * q + 1 & 3) + 8 * (2 * q + 1 >> 2) + 4 * hi;
            ob[(size_t)c0 * CH_STRIDE] = fmaf(a3[2 * q],     s.x, a2[2 * q]);
            ob[(size_t)c1 * CH_STRIDE] = fmaf(a3[2 * q + 1], s.y, a2[2 * q + 1]);
        }
    };

    // one plane step: X completes (output q-sgn), Y mid, Z starts (output q+sgn)
    auto step = [&](int i, f32x16& X, f32x16& Y, f32x16& Z) {
        if (i > BD) return;                        // uniform guard
        int q = d0 + sgn * i;                      // plane index (OOB at i==BD)
        if (i + 2 < BD) stage(d0 + sgn * (i + 2)); // 2-ahead prefetch
        if (i < BD) {
            const char* sb = slab[q & 3];
            #pragma unroll
            for (int t = 0; t < 9; ++t) {
                bf16x8 B = *(const bf16x8*)(sb + (t / 3) * 4224 + bpo[t % 3]);
                X = __builtin_amdgcn_mfma_f32_32x32x16_bf16(afA[t], B, X, 0, 0, 0);
                Y = __builtin_amdgcn_mfma_f32_32x32x16_bf16(afB[t], B, Y, 0, 0, 0);
                Z = __builtin_amdgcn_mfma_f32_32x32x16_bf16(afC[t], B, Z, 0, 0, 0);
            }
        }
        if (i >= 1) tail(X, q - sgn);              // output q-sgn now complete
        X = zacc;                                  // X becomes next step's Z
        __syncthreads();                           // staged plane landed
    };

    // prologue: planes for steps 0 and 1 in flight
    stage(d0);
    stage(d0 + sgn);
    __syncthreads();

    f32x16 accA = zacc, accB = zacc, accC = zacc;
    #pragma unroll 1
    for (int i = 0; i <= BD; i += 3) {             // 32 logical steps (0..31)
        step(i,     accA, accB, accC);
        step(i + 1, accB, accC, accA);
        step(i + 2, accC, accA, accB);
    }
}

extern "C" void kernel_launch(void* const* d_in, const int* in_sizes, int n_in,
                              void* d_out, int out_size, void* d_ws, size_t ws_size,
                              hipStream_t stream)
{
    const float* inp = (const float*)d_in[0];
    const float* cw  = (const float*)d_in[1];
    const float* w1  = (const float*)d_in[2];
    const float* w2  = (const float*)d_in[3];
    const float* w3  = (const float*)d_in[4];
    const int*   rev = (const int*)d_in[5];

    ushort* wtab  = (ushort*)d_ws;                    // [0, 27648)
    ushort* wtab2 = (ushort*)((char*)d_ws + 27648);   // [27648, 31744)
    char*   xT    = (char*)d_ws + 32768;              // 65,011,712 B

    wprep_all<<<dim3(62), dim3(256), 0, stream>>>(cw, w1, w2, w3, wtab, wtab2);

    xprep_kernel<<<dim3(7936), dim3(256), 0, stream>>>(inp, xT);

    // 4b x 128ht = 512 blocks (2 per CU), persistent over all 31 d
    qrnn_fused<<<dim3(512), dim3(256), 0, stream>>>(
        xT, wtab, wtab2, (float*)d_out, rev);
}

// Round 16
// 132.742 us; speedup vs baseline: 1.1247x; 1.0015x over previous
//
#include <hip/hip_runtime.h>
#include <hip/hip_fp16.h>

#define HC 16
#define CIN 16
#define BD 31
#define HH 128
#define WW 128
#define PLANE (HH*WW)           // 16384
#define CH_STRIDE (BD*PLANE)    // 507904

typedef __attribute__((ext_vector_type(8))) short bf16x8;   // 8 bf16 = 4 VGPR
typedef __attribute__((ext_vector_type(16))) float f32x16;  // MFMA 32x32 acc

__device__ __forceinline__ ushort f2bf(float f) {   // RNE float->bf16 (prep paths)
    unsigned u = __float_as_uint(f);
    u = (u + 0x7fffu + ((u >> 16) & 1u)) >> 16;
    return (ushort)u;
}
// packed f32x2 -> bf16x2 via HW cvt_pk (no builtin on gfx950 — inline asm, T12)
__device__ __forceinline__ unsigned pack_bf2(float lo, float hi) {
    unsigned r;
    asm("v_cvt_pk_bf16_f32 %0, %1, %2" : "=v"(r) : "v"(lo), "v"(hi));
    return r;
}
// paired sigmoids: sig(a), sig(b) with ONE rcp (TRANS is quarter-rate).
__device__ __forceinline__ float2 sigmoid2(float a, float b) {
    float ea = __expf(-a);
    float eb = __expf(-b);
    float pa = 1.0f + ea, pb = 1.0f + eb;
    float r  = __builtin_amdgcn_rcpf(pa * pb);
    return make_float2(pb * r, pa * r);      // 1/pa, 1/pb
}
// paired tanh-form gelus (|err vs exact-erf gelu| <~5e-4), shared rcp:
// gelu(x) = x * sigma(1.5957691*(x + 0.044715*x^3))
__device__ __forceinline__ float2 gelu2(float x, float y) {
    float ux = fmaf(0.044715f * x, x * x, x);
    float uy = fmaf(0.044715f * y, y * y, y);
    float ex = __expf(-1.5957691f * ux);
    float ey = __expf(-1.5957691f * uy);
    float px = 1.0f + ex, py = 1.0f + ey;
    float r  = __builtin_amdgcn_rcpf(px * py);
    return make_float2(x * py * r, y * px * r);
}

// ---------------------------------------------------------------------------
// xprep + weight prep in ONE launch (r12 pattern). Blocks < 7936: fp32 ->
// bf16 rows xT[b][d][h][4096B], slab swizzle pre-baked (swizzle-source +
// linear gload_lds dest, rule #21). Blocks >= 7936 (62): conv wtab
// (co=lane&31, ci=8*(lane>>5)+j) and MLP wtab2 (shared k-map
// k(e,hi)=(e&3)+8*(e>>2)+4*hi on all tables).
// ---------------------------------------------------------------------------
__global__ __launch_bounds__(256)
void xprep_kernel(const float* __restrict__ inp, char* __restrict__ xT,
                  const float* __restrict__ cw,
                  const float* __restrict__ w1,
                  const float* __restrict__ w2,
                  const float* __restrict__ w3,
                  ushort* __restrict__ wtab, ushort* __restrict__ wtab2)
{
    if (blockIdx.x >= 7936) {                 // weight-prep blocks
        int idx = (blockIdx.x - 7936) * 256 + threadIdx.x;
        if (idx < 13824) {
            int j    = idx & 7;
            int lane = (idx >> 3) & 63;
            int t    = (idx >> 9) % 9;
            int kd   = (idx >> 9) / 9;
            int co = lane & 31;
            int ci = 8 * (lane >> 5) + j;
            int kh = t / 3, kw = t % 3;
            wtab[idx] = f2bf(cw[(co * CIN + ci) * 27 + kd * 9 + kh * 3 + kw]);
            return;
        }
        idx -= 13824;
        if (idx >= 2048) return;
        int e    = idx & 7;
        int lane = (idx >> 3) & 63;
        int tbl  = idx >> 9;
        int m  = lane & 31;
        int hi = lane >> 5;
        int k  = (e & 3) + 8 * (e >> 2) + 4 * hi;   // shared k-permutation
        float v = 0.f;
        if (tbl == 0)      v = w1[k * 32 + m];
        else if (tbl == 3) v = w3[k * 32 + m];
        else {
            int mf = tbl - 1;
            if (m < 16) v = w2[(k + 16 * mf) * 16 + m];
        }
        wtab2[idx] = f2bf(v);
        return;
    }

    __shared__ float tile[16][256];
    int t  = threadIdx.x;
    int hp = blockIdx.x & 63;
    int g  = blockIdx.x >> 6;
    int d  = g % BD;
    int b  = g / BD;

    size_t src = (size_t)b * CIN * CH_STRIDE + (size_t)d * PLANE + hp * 256;
    #pragma unroll
    for (int c = 0; c < 16; ++c)
        tile[c][t] = inp[src + (size_t)c * CH_STRIDE + t];
    __syncthreads();

    int w  = t & 127;
    int rr = t >> 7;
    char* rowp = xT + (((size_t)(b * BD + d) * 128) + hp * 2 + rr) * 4096;
    #pragma unroll
    for (int q = 0; q < 2; ++q) {
        uint4 pk;
        pk.x = (unsigned)f2bf(tile[q*8+0][t]) | ((unsigned)f2bf(tile[q*8+1][t]) << 16);
        pk.y = (unsigned)f2bf(tile[q*8+2][t]) | ((unsigned)f2bf(tile[q*8+3][t]) << 16);
        pk.z = (unsigned)f2bf(tile[q*8+4][t]) | ((unsigned)f2bf(tile[q*8+5][t]) << 16);
        pk.w = (unsigned)f2bf(tile[q*8+6][t]) | ((unsigned)f2bf(tile[q*8+7][t]) << 16);
        unsigned off = ((unsigned)((w + 1) * 32 + q * 16) ^ (((unsigned)(w + 1) & 0xE) << 3)) - 32;
        *(uint4*)(rowp + off) = pk;
    }
}

// ---------------------------------------------------------------------------
// FUSED conv+scan+MLP (r14 structure — measured best) with the conv's 27-deep
// serial MFMA chain split into TWO independent interleaved chains (odd/even
// taps), summed at the end: halves the dependent-MFMA latency chain at the
// cost of +1 f32x16 and 16 adds. Everything else identical to r14.
// ---------------------------------------------------------------------------
#define SLOT_B (3 * 4224)       // 12672 B per plane slot

__device__ __forceinline__ void gload_lds16(const void* g, void* l) {
    __builtin_amdgcn_global_load_lds(
        (const __attribute__((address_space(1))) unsigned int*)g,
        (__attribute__((address_space(3))) unsigned int*)l, 16, 0, 0);
}

__global__ __launch_bounds__(256, 2)
void qrnn_fused(const char* __restrict__ xT,
                const ushort* __restrict__ wtab,
                const ushort* __restrict__ wtab2,
                float* __restrict__ out,
                const int* __restrict__ rev_p)
{
    __shared__ __align__(16) char slab[4][SLOT_B];

    // grid 512 = 8 XCD x 64
    int p = blockIdx.x;
    int logical = (p & 7) * 64 + (p >> 3);
    int b  = logical >> 7;
    int ht = logical & 127;
    int rev = rev_p[0];

    int lane = threadIdx.x & 63;
    int wid  = threadIdx.x >> 6;
    int wl   = lane & 31;
    int hi   = lane >> 5;
    int cio  = hi * 16;

    const bf16x8* wt = (const bf16x8*)wtab;
    bf16x8 af[27];
    #pragma unroll
    for (int t = 0; t < 27; ++t) af[t] = wt[t * 64 + lane];

    const bf16x8* W2 = (const bf16x8*)wtab2;
    bf16x8 af1  = W2[lane];
    bf16x8 af2a = W2[64 + lane];
    bf16x8 af2b = W2[128 + lane];
    bf16x8 af3  = W2[192 + lane];

    unsigned bpo[3];
    #pragma unroll
    for (int dwn = 0; dwn < 3; ++dwn) {
        unsigned wc = (unsigned)(wl + dwn);
        bpo[dwn] = (unsigned)(wid * 1024) + ((wc * 32 + cio) ^ ((wc & 0xE) << 3));
    }

    for (int i = threadIdx.x; i < 4 * 3 * 32; i += 256) {
        int s = i / 96;
        int r = (i / 32) % 3;
        int k = i & 31;
        int off = (k < 8) ? (k * 4) : (4128 + (k - 8) * 4);
        *(int*)(slab[s] + r * 4224 + off) = 0;
    }

    auto zero_slot = [&](int s) {
        for (int i = threadIdx.x; i < 768; i += 256) {
            int r = i >> 8;
            int k = i & 255;
            *(uint4*)(slab[s] + r * 4224 + 32 + k * 16) = uint4{0, 0, 0, 0};
        }
    };

    auto stage = [&](int s, int plane) {
        const char* pl = xT + ((size_t)(b * BD + plane) * 128) * 4096;
        for (int c = wid; c < 12; c += 4) {
            int rr = c >> 2, ch = c & 3;
            int h = ht - 1 + rr;
            char* dst = slab[s] + rr * 4224 + 32 + ch * 1024;
            if ((unsigned)h < (unsigned)HH)
                gload_lds16(pl + (size_t)h * 4096 + ch * 1024 + lane * 16, dst);
            else
                *(uint4*)(dst + lane * 16) = uint4{0, 0, 0, 0};
        }
    };

    f32x16 zacc;
    #pragma unroll
    for (int r = 0; r < 16; ++r) zacc[r] = 0.f;

    // conv for output d: 27 MFMAs split into two independent chains (odd/even
    // taps, interleaved in program order), summed at the end.
    auto convd = [&](int d) -> f32x16 {
        f32x16 A = zacc, B2 = zacc;
        #pragma unroll
        for (int kd = 0; kd < 3; ++kd) {
            const char* sb = slab[(d - 1 + kd) & 3];   // OOB slots hold zeros
            #pragma unroll
            for (int t = 0; t < 9; ++t) {
                bf16x8 bfr = *(const bf16x8*)(sb + (t / 3) * 4224 + bpo[t % 3]);
                int g = kd * 9 + t;
                if (g & 1)
                    A  = __builtin_amdgcn_mfma_f32_32x32x16_bf16(af[g], bfr, A, 0, 0, 0);
                else
                    B2 = __builtin_amdgcn_mfma_f32_32x32x16_bf16(af[g], bfr, B2, 0, 0, 0);
            }
        }
        #pragma unroll
        for (int r = 0; r < 16; ++r) A[r] += B2[r];
        return A;
    };

    float h[8];
    #pragma unroll
    for (int j = 0; j < 8; ++j) h[j] = 0.f;

    float* obase = out + (size_t)b * HC * CH_STRIDE + ht * WW + wid * 32 + wl;

    // tail: gates -> scan -> MLP -> store for plane d, given conv acc A.
    auto tail = [&](const f32x16& A, int d) {
        union { bf16x8 v; unsigned u[4]; } bx;
        #pragma unroll
        for (int r = 0; r < 8; ++r) {
            float2 s = sigmoid2(2.0f * A[r], A[r + 8]);
            float z = fmaf(2.0f, s.x, -1.0f);    // tanh via sigmoid
            float f = s.y;
            h[r] = z + f * (h[r] - z);           // f*h + (1-f)*z
        }
        #pragma unroll
        for (int q = 0; q < 4; ++q)
            bx.u[q] = pack_bf2(h[2 * q], h[2 * q + 1]);

        f32x16 a1 = __builtin_amdgcn_mfma_f32_32x32x16_bf16(af1, bx.v, zacc, 0, 0, 0);
        f32x16 a3 = __builtin_amdgcn_mfma_f32_32x32x16_bf16(af3, bx.v, zacc, 0, 0, 0);

        union { bf16x8 v; unsigned u[4]; } b2a, b2b;
        #pragma unroll
        for (int q = 0; q < 4; ++q) {
            float2 ga = gelu2(a1[2 * q],     a1[2 * q + 1]);
            float2 gb = gelu2(a1[8 + 2 * q], a1[8 + 2 * q + 1]);
            b2a.u[q] = pack_bf2(ga.x, ga.y);
            b2b.u[q] = pack_bf2(gb.x, gb.y);
        }
        f32x16 a2 = __builtin_amdgcn_mfma_f32_32x32x16_bf16(af2a, b2a.v, zacc, 0, 0, 0);
        a2 = __builtin_amdgcn_mfma_f32_32x32x16_bf16(af2b, b2b.v, a2, 0, 0, 0);

        float* ob = obase + (size_t)d * PLANE;
        #pragma unroll
        for (int q = 0; q < 4; ++q) {
            float2 s = sigmoid2(a3[8 + 2 * q], a3[9 + 2 * q]);
            int c0 = (2 * q     & 3) + 8 * (2 * q     >> 2) + 4 * hi;
            int c1 = (2 * q + 1 & 3) + 8 * (2 * q + 1 >> 2) + 4 * hi;
            ob[(size_t)c0 * CH_STRIDE] = fmaf(a3[2 * q],     s.x, a2[2 * q]);
            ob[(size_t)c1 * CH_STRIDE] = fmaf(a3[2 * q + 1], s.y, a2[2 * q + 1]);
        }
    };

    int d0  = rev ? (BD - 1) : 0;
    int sgn = rev ? -1 : 1;
    int oobq = rev ? -1 : BD;

    stage(d0 & 3, d0);
    stage((d0 + sgn) & 3, d0 + sgn);
    zero_slot((d0 - sgn) & 3);
    __syncthreads();

    f32x16 accP;
    {
        int q = d0 + 2 * sgn;
        if (q >= 0 && q < BD) stage(q & 3, q);
        accP = convd(d0);
        __syncthreads();
    }

    #pragma unroll 1
    for (int i = 1; i < BD; ++i) {
        int d = d0 + sgn * i;
        int q = d + 2 * sgn;
        if (q >= 0 && q < BD) stage(q & 3, q);
        else if (q == oobq)   zero_slot(q & 3);

        f32x16 acc = convd(d);      // 2 interleaved 13/14-deep MFMA chains
        tail(accP, d - sgn);        // VALU/TRANS chain for previous d
        accP = acc;

        __syncthreads();
    }
    tail(accP, d0 + sgn * (BD - 1));
}

extern "C" void kernel_launch(void* const* d_in, const int* in_sizes, int n_in,
                              void* d_out, int out_size, void* d_ws, size_t ws_size,
                              hipStream_t stream)
{
    const float* inp = (const float*)d_in[0];
    const float* cw  = (const float*)d_in[1];
    const float* w1  = (const float*)d_in[2];
    const float* w2  = (const float*)d_in[3];
    const float* w3  = (const float*)d_in[4];
    const int*   rev = (const int*)d_in[5];

    ushort* wtab  = (ushort*)d_ws;                    // [0, 27648)
    ushort* wtab2 = (ushort*)((char*)d_ws + 27648);   // [27648, 31744)
    char*   xT    = (char*)d_ws + 32768;              // 65,011,712 B

    // 7936 xprep blocks + 62 weight-prep blocks, one launch
    xprep_kernel<<<dim3(7998), dim3(256), 0, stream>>>(
        inp, xT, cw, w1, w2, w3, wtab, wtab2);

    // 4b x 128ht = 512 blocks (2 per CU), persistent over all 31 d
    qrnn_fused<<<dim3(512), dim3(256), 0, stream>>>(
        xT, wtab, wtab2, (float*)d_out, rev);
}

// Round 17
// 128.821 us; speedup vs baseline: 1.1590x; 1.0304x over previous
//
#include <hip/hip_runtime.h>
#include <hip/hip_fp16.h>

#define HC 16
#define CIN 16
#define BD 31
#define HH 128
#define WW 128
#define PLANE (HH*WW)           // 16384
#define CH_STRIDE (BD*PLANE)    // 507904

typedef __attribute__((ext_vector_type(8))) short bf16x8;   // 8 bf16 = 4 VGPR
typedef __attribute__((ext_vector_type(16))) float f32x16;  // MFMA 32x32 acc

#define LOG2E 1.442695041f

__device__ __forceinline__ ushort f2bf(float f) {   // RNE float->bf16 (prep paths)
    unsigned u = __float_as_uint(f);
    u = (u + 0x7fffu + ((u >> 16) & 1u)) >> 16;
    return (ushort)u;
}
// packed f32x2 -> bf16x2 via HW cvt_pk (no builtin on gfx950 — inline asm, T12)
__device__ __forceinline__ unsigned pack_bf2(float lo, float hi) {
    unsigned r;
    asm("v_cvt_pk_bf16_f32 %0, %1, %2" : "=v"(r) : "v"(lo), "v"(hi));
    return r;
}
// paired sigmoids from log2-domain negated args: returns (sig(a), sig(b))
// where na = -a*log2e, nb = -b*log2e. One shared rcp; exp via v_exp_f32
// directly (ln2 folded into the callers' pre-scale constants).
__device__ __forceinline__ float2 sigmoid2l(float na, float nb) {
    float ea = __builtin_amdgcn_exp2f(na);
    float eb = __builtin_amdgcn_exp2f(nb);
    float pa = 1.0f + ea, pb = 1.0f + eb;
    float r  = __builtin_amdgcn_rcpf(pa * pb);
    return make_float2(pb * r, pa * r);      // 1/pa, 1/pb
}
// paired tanh-form gelus (|err vs exact-erf gelu| <~5e-4), shared rcp:
// gelu(x) = x * sigma(1.5957691*(x + 0.044715*x^3)); 1.5957691*log2e = 2.3021841
__device__ __forceinline__ float2 gelu2(float x, float y) {
    float ux = fmaf(0.044715f * x, x * x, x);
    float uy = fmaf(0.044715f * y, y * y, y);
    float ex = __builtin_amdgcn_exp2f(-2.3021841f * ux);
    float ey = __builtin_amdgcn_exp2f(-2.3021841f * uy);
    float px = 1.0f + ex, py = 1.0f + ey;
    float r  = __builtin_amdgcn_rcpf(px * py);
    return make_float2(x * py * r, y * px * r);
}

// ---------------------------------------------------------------------------
// xprep + weight prep in ONE launch. Blocks < 7936: fp32 -> bf16 rows
// xT[b][d][h][4096B], slab swizzle pre-baked (swizzle-source + linear
// gload_lds dest, rule #21). Blocks >= 7936 (62): conv wtab (co=lane&31,
// ci=8*(lane>>5)+j) and MLP wtab2 (shared k-map k(e,hi)=(e&3)+8*(e>>2)+4*hi).
// ---------------------------------------------------------------------------
__global__ __launch_bounds__(256)
void xprep_kernel(const float* __restrict__ inp, char* __restrict__ xT,
                  const float* __restrict__ cw,
                  const float* __restrict__ w1,
                  const float* __restrict__ w2,
                  const float* __restrict__ w3,
                  ushort* __restrict__ wtab, ushort* __restrict__ wtab2)
{
    if (blockIdx.x >= 7936) {                 // weight-prep blocks
        int idx = (blockIdx.x - 7936) * 256 + threadIdx.x;
        if (idx < 13824) {
            int j    = idx & 7;
            int lane = (idx >> 3) & 63;
            int t    = (idx >> 9) % 9;
            int kd   = (idx >> 9) / 9;
            int co = lane & 31;
            int ci = 8 * (lane >> 5) + j;
            int kh = t / 3, kw = t % 3;
            wtab[idx] = f2bf(cw[(co * CIN + ci) * 27 + kd * 9 + kh * 3 + kw]);
            return;
        }
        idx -= 13824;
        if (idx >= 2048) return;
        int e    = idx & 7;
        int lane = (idx >> 3) & 63;
        int tbl  = idx >> 9;
        int m  = lane & 31;
        int hi = lane >> 5;
        int k  = (e & 3) + 8 * (e >> 2) + 4 * hi;   // shared k-permutation
        float v = 0.f;
        if (tbl == 0)      v = w1[k * 32 + m];
        else if (tbl == 3) v = w3[k * 32 + m];
        else {
            int mf = tbl - 1;
            if (m < 16) v = w2[(k + 16 * mf) * 16 + m];
        }
        wtab2[idx] = f2bf(v);
        return;
    }

    __shared__ float tile[16][256];
    int t  = threadIdx.x;
    int hp = blockIdx.x & 63;
    int g  = blockIdx.x >> 6;
    int d  = g % BD;
    int b  = g / BD;

    size_t src = (size_t)b * CIN * CH_STRIDE + (size_t)d * PLANE + hp * 256;
    #pragma unroll
    for (int c = 0; c < 16; ++c)
        tile[c][t] = inp[src + (size_t)c * CH_STRIDE + t];
    __syncthreads();

    int w  = t & 127;
    int rr = t >> 7;
    char* rowp = xT + (((size_t)(b * BD + d) * 128) + hp * 2 + rr) * 4096;
    #pragma unroll
    for (int q = 0; q < 2; ++q) {
        uint4 pk;
        pk.x = (unsigned)f2bf(tile[q*8+0][t]) | ((unsigned)f2bf(tile[q*8+1][t]) << 16);
        pk.y = (unsigned)f2bf(tile[q*8+2][t]) | ((unsigned)f2bf(tile[q*8+3][t]) << 16);
        pk.z = (unsigned)f2bf(tile[q*8+4][t]) | ((unsigned)f2bf(tile[q*8+5][t]) << 16);
        pk.w = (unsigned)f2bf(tile[q*8+6][t]) | ((unsigned)f2bf(tile[q*8+7][t]) << 16);
        unsigned off = ((unsigned)((w + 1) * 32 + q * 16) ^ (((unsigned)(w + 1) & 0xE) << 3)) - 32;
        *(uint4*)(rowp + off) = pk;
    }
}

// ---------------------------------------------------------------------------
// FUSED conv+scan+MLP — r14 structure (measured-best fused: 98.8 µs):
// single-chain convd (r16's odd/even split regressed to 105), software-
// pipelined conv(d) ∥ tail(d-1), TRANS-reduced tail with exp2-folded
// activations. One barrier per d; 4 rolling plane slots.
// ---------------------------------------------------------------------------
#define SLOT_B (3 * 4224)       // 12672 B per plane slot

__device__ __forceinline__ void gload_lds16(const void* g, void* l) {
    __builtin_amdgcn_global_load_lds(
        (const __attribute__((address_space(1))) unsigned int*)g,
        (__attribute__((address_space(3))) unsigned int*)l, 16, 0, 0);
}

__global__ __launch_bounds__(256, 2)
void qrnn_fused(const char* __restrict__ xT,
                const ushort* __restrict__ wtab,
                const ushort* __restrict__ wtab2,
                float* __restrict__ out,
                const int* __restrict__ rev_p)
{
    __shared__ __align__(16) char slab[4][SLOT_B];

    // grid 512 = 8 XCD x 64
    int p = blockIdx.x;
    int logical = (p & 7) * 64 + (p >> 3);
    int b  = logical >> 7;
    int ht = logical & 127;
    int rev = rev_p[0];

    int lane = threadIdx.x & 63;
    int wid  = threadIdx.x >> 6;
    int wl   = lane & 31;
    int hi   = lane >> 5;
    int cio  = hi * 16;

    const bf16x8* wt = (const bf16x8*)wtab;
    bf16x8 af[27];
    #pragma unroll
    for (int t = 0; t < 27; ++t) af[t] = wt[t * 64 + lane];

    const bf16x8* W2 = (const bf16x8*)wtab2;
    bf16x8 af1  = W2[lane];
    bf16x8 af2a = W2[64 + lane];
    bf16x8 af2b = W2[128 + lane];
    bf16x8 af3  = W2[192 + lane];

    unsigned bpo[3];
    #pragma unroll
    for (int dwn = 0; dwn < 3; ++dwn) {
        unsigned wc = (unsigned)(wl + dwn);
        bpo[dwn] = (unsigned)(wid * 1024) + ((wc * 32 + cio) ^ ((wc & 0xE) << 3));
    }

    for (int i = threadIdx.x; i < 4 * 3 * 32; i += 256) {
        int s = i / 96;
        int r = (i / 32) % 3;
        int k = i & 31;
        int off = (k < 8) ? (k * 4) : (4128 + (k - 8) * 4);
        *(int*)(slab[s] + r * 4224 + off) = 0;
    }

    auto zero_slot = [&](int s) {
        for (int i = threadIdx.x; i < 768; i += 256) {
            int r = i >> 8;
            int k = i & 255;
            *(uint4*)(slab[s] + r * 4224 + 32 + k * 16) = uint4{0, 0, 0, 0};
        }
    };

    auto stage = [&](int s, int plane) {
        const char* pl = xT + ((size_t)(b * BD + plane) * 128) * 4096;
        for (int c = wid; c < 12; c += 4) {
            int rr = c >> 2, ch = c & 3;
            int h = ht - 1 + rr;
            char* dst = slab[s] + rr * 4224 + 32 + ch * 1024;
            if ((unsigned)h < (unsigned)HH)
                gload_lds16(pl + (size_t)h * 4096 + ch * 1024 + lane * 16, dst);
            else
                *(uint4*)(dst + lane * 16) = uint4{0, 0, 0, 0};
        }
    };

    f32x16 zacc;
    #pragma unroll
    for (int r = 0; r < 16; ++r) zacc[r] = 0.f;

    // conv for output d: single 27-MFMA chain (measured best vs split forms)
    auto convd = [&](int d) -> f32x16 {
        f32x16 A = zacc;
        #pragma unroll
        for (int kd = 0; kd < 3; ++kd) {
            const char* sb = slab[(d - 1 + kd) & 3];   // OOB slots hold zeros
            #pragma unroll
            for (int t = 0; t < 9; ++t) {
                bf16x8 bfr = *(const bf16x8*)(sb + (t / 3) * 4224 + bpo[t % 3]);
                A = __builtin_amdgcn_mfma_f32_32x32x16_bf16(af[kd * 9 + t], bfr, A, 0, 0, 0);
            }
        }
        return A;
    };

    float h[8];
    #pragma unroll
    for (int j = 0; j < 8; ++j) h[j] = 0.f;

    float* obase = out + (size_t)b * HC * CH_STRIDE + ht * WW + wid * 32 + wl;

    // tail: gates -> scan -> MLP -> store for plane d, given conv acc A.
    auto tail = [&](const f32x16& A, int d) {
        union { bf16x8 v; unsigned u[4]; } bx;
        #pragma unroll
        for (int r = 0; r < 8; ++r) {
            // z = tanh(a) = 2*sig(2a)-1 -> exp2 arg -2a*log2e; f = sig(b)
            float2 s = sigmoid2l(-2.0f * LOG2E * A[r], -LOG2E * A[r + 8]);
            float z = fmaf(2.0f, s.x, -1.0f);
            float f = s.y;
            h[r] = z + f * (h[r] - z);           // f*h + (1-f)*z
        }
        #pragma unroll
        for (int q = 0; q < 4; ++q)
            bx.u[q] = pack_bf2(h[2 * q], h[2 * q + 1]);

        f32x16 a1 = __builtin_amdgcn_mfma_f32_32x32x16_bf16(af1, bx.v, zacc, 0, 0, 0);
        f32x16 a3 = __builtin_amdgcn_mfma_f32_32x32x16_bf16(af3, bx.v, zacc, 0, 0, 0);

        union { bf16x8 v; unsigned u[4]; } b2a, b2b;
        #pragma unroll
        for (int q = 0; q < 4; ++q) {
            float2 ga = gelu2(a1[2 * q],     a1[2 * q + 1]);
            float2 gb = gelu2(a1[8 + 2 * q], a1[8 + 2 * q + 1]);
            b2a.u[q] = pack_bf2(ga.x, ga.y);
            b2b.u[q] = pack_bf2(gb.x, gb.y);
        }
        f32x16 a2 = __builtin_amdgcn_mfma_f32_32x32x16_bf16(af2a, b2a.v, zacc, 0, 0, 0);
        a2 = __builtin_amdgcn_mfma_f32_32x32x16_bf16(af2b, b2b.v, a2, 0, 0, 0);

        float* ob = obase + (size_t)d * PLANE;
        #pragma unroll
        for (int q = 0; q < 4; ++q) {
            float2 s = sigmoid2l(-LOG2E * a3[8 + 2 * q], -LOG2E * a3[9 + 2 * q]);
            int c0 = (2 * q     & 3) + 8 * (2 * q     >> 2) + 4 * hi;
            int c1 = (2 * q + 1 & 3) + 8 * (2 * q + 1 >> 2) + 4 * hi;
            ob[(size_t)c0 * CH_STRIDE] = fmaf(a3[2 * q],     s.x, a2[2 * q]);
            ob[(size_t)c1 * CH_STRIDE] = fmaf(a3[2 * q + 1], s.y, a2[2 * q + 1]);
        }
    };

    int d0  = rev ? (BD - 1) : 0;
    int sgn = rev ? -1 : 1;
    int oobq = rev ? -1 : BD;

    stage(d0 & 3, d0);
    stage((d0 + sgn) & 3, d0 + sgn);
    zero_slot((d0 - sgn) & 3);
    __syncthreads();

    f32x16 accP;
    {
        int q = d0 + 2 * sgn;
        if (q >= 0 && q < BD) stage(q & 3, q);
        accP = convd(d0);
        __syncthreads();
    }

    #pragma unroll 1
    for (int i = 1; i < BD; ++i) {
        int d = d0 + sgn * i;
        int q = d + 2 * sgn;
        if (q >= 0 && q < BD) stage(q & 3, q);
        else if (q == oobq)   zero_slot(q & 3);

        f32x16 acc = convd(d);      // 27 MFMAs — independent of tail below
        tail(accP, d - sgn);        // VALU/TRANS chain for previous d
        accP = acc;

        __syncthreads();
    }
    tail(accP, d0 + sgn * (BD - 1));
}

extern "C" void kernel_launch(void* const* d_in, const int* in_sizes, int n_in,
                              void* d_out, int out_size, void* d_ws, size_t ws_size,
                              hipStream_t stream)
{
    const float* inp = (const float*)d_in[0];
    const float* cw  = (const float*)d_in[1];
    const float* w1  = (const float*)d_in[2];
    const float* w2  = (const float*)d_in[3];
    const float* w3  = (const float*)d_in[4];
    const int*   rev = (const int*)d_in[5];

    ushort* wtab  = (ushort*)d_ws;                    // [0, 27648)
    ushort* wtab2 = (ushort*)((char*)d_ws + 27648);   // [27648, 31744)
    char*   xT    = (char*)d_ws + 32768;              // 65,011,712 B

    // 7936 xprep blocks + 62 weight-prep blocks, one launch
    xprep_kernel<<<dim3(7998), dim3(256), 0, stream>>>(
        inp, xT, cw, w1, w2, w3, wtab, wtab2);

    // 4b x 128ht = 512 blocks (2 per CU), persistent over all 31 d
    qrnn_fused<<<dim3(512), dim3(256), 0, stream>>>(
        xT, wtab, wtab2, (float*)d_out, rev);
}